// Round 8
// baseline (82.343 us; speedup 1.0000x reference)
//
#include <hip/hip_runtime.h>

// GIoU max-match loss: out = (1/B) * sum_{b,p} (1 - max_g GIoU(pred[b,p], tgt[b,g]))
// B=32, P=2048, G=512 in the bench shapes.
//
// R8: EXACT spatial pruning. R2-R7 showed cost ~ #pairs (33.5M) with all
// micro-variants flat at ~31-36 us; so reduce pairs.
//   prep kernel (block/batch): counting-sort targets and preds into an 8x8
//     cell grid (cell from box center). Per target-cell: center bbox, max
//     area, max half-extents (float atomics via int, all values >= 0).
//   main kernel: lane = one SORTED pred (waves spatially coherent). Seed the
//     running max from the pred's own cell, then scan 64 cells; a cell is
//     skipped when a PROVABLE upper bound on giou+1 for every target in it
//     is <= current max:
//       overlap impossible when dx >= pw/2 + max tw/2 (dx = center-to-bbox
//       distance; ow >= |pxc-txc| and ow >= pw), then
//       gi+1 = (pa+ta)/outer <= (pa + taMax) / (max(pw,dx)*max(ph,dy)).
//     Eval loops are cell-major -> wave-uniform bounds, broadcast LDS reads.
//     Pruning is upper-bound-exact; re-evals are idempotent under max.
//   reduce kernel: sums per-block partials.
// Math (w,h >= 1 after +1 fold): outer via a+b-min identity; giou+1 = num/den,
//   num = un^2 + inter*outer, den = un*outer; running max by cross-mult
//   (division-free); products <= ~5e19 fit fp32. Reference's [-1,1] clip and
//   1e-6 iou floor are no-ops at the 42.24 absmax threshold.

constexpr int NCX = 8, NCY = 8, NCELL = NCX * NCY;
constexpr int GMAXL = 2048;     // LDS capacity for sorted targets (bench: 512)

__device__ __forceinline__ int cell_of(float xc, float yc) {
    int cx = (int)(xc * (1.0f / 128.0f)); cx = max(0, min(NCX - 1, cx));
    int cy = (int)(yc * (1.0f / 128.0f)); cy = max(0, min(NCY - 1, cy));
    return cy * NCX + cx;
}

__global__ __launch_bounds__(512) void giou_prep_kernel(
    const float4* __restrict__ tgt, const float4* __restrict__ pred,
    float4* __restrict__ sortedT, float* __restrict__ sTA,
    float4* __restrict__ sortedP,
    int* __restrict__ tstartG, float4* __restrict__ meta0G, float4* __restrict__ meta1G,
    int* __restrict__ tmpc, int* __restrict__ tmpr,
    int* __restrict__ pmpc, int* __restrict__ pmpr,
    int P, int G)
{
    __shared__ int cnt[NCELL], cstart[NCELL + 1];
    __shared__ int bminx[NCELL], bminy[NCELL], bmaxx[NCELL], bmaxy[NCELL];
    __shared__ int taM[NCELL], twM[NCELL], thM[NCELL];

    const int b = blockIdx.x, tid = threadIdx.x;
    if (tid < NCELL) {
        cnt[tid] = 0;
        bminx[tid] = 0x7f800000; bminy[tid] = 0x7f800000;   // +inf
        bmaxx[tid] = 0; bmaxy[tid] = 0;
        taM[tid] = 0; twM[tid] = 0; thM[tid] = 0;
    }
    __syncthreads();

    // ---- targets: count + per-cell stats ----
    for (int g = tid; g < G; g += 512) {
        float4 t = tgt[b * G + g]; t.z += 1.0f; t.w += 1.0f;
        float xc = (t.x + t.z) * 0.5f, yc = (t.y + t.w) * 0.5f;
        int c = cell_of(xc, yc);
        int r = atomicAdd(&cnt[c], 1);
        tmpc[b * G + g] = c; tmpr[b * G + g] = r;
        atomicMin(&bminx[c], __float_as_int(xc));
        atomicMin(&bminy[c], __float_as_int(yc));
        atomicMax(&bmaxx[c], __float_as_int(xc));
        atomicMax(&bmaxy[c], __float_as_int(yc));
        float tw = t.z - t.x, th = t.w - t.y;
        atomicMax(&taM[c], __float_as_int(tw * th));
        atomicMax(&twM[c], __float_as_int(tw * 0.5f));
        atomicMax(&thM[c], __float_as_int(th * 0.5f));
    }
    __syncthreads();
    if (tid == 0) {
        int s = 0;
        for (int c = 0; c < NCELL; ++c) { cstart[c] = s; s += cnt[c]; }
        cstart[NCELL] = s;
    }
    __syncthreads();
    for (int g = tid; g < G; g += 512) {
        float4 t = tgt[b * G + g]; t.z += 1.0f; t.w += 1.0f;
        int pos = cstart[tmpc[b * G + g]] + tmpr[b * G + g];
        sortedT[b * G + pos] = t;
        sTA[b * G + pos] = (t.z - t.x) * (t.w - t.y);
    }
    if (tid <= NCELL) tstartG[b * (NCELL + 1) + tid] = cstart[tid];
    if (tid < NCELL) {
        meta0G[b * NCELL + tid] = make_float4(
            __int_as_float(bminx[tid]), __int_as_float(bminy[tid]),
            __int_as_float(bmaxx[tid]), __int_as_float(bmaxy[tid]));
        meta1G[b * NCELL + tid] = make_float4(
            __int_as_float(taM[tid]), __int_as_float(twM[tid]),
            __int_as_float(thM[tid]), 0.0f);
    }

    // ---- preds: counting sort ----
    __syncthreads();
    if (tid < NCELL) cnt[tid] = 0;
    __syncthreads();
    for (int p = tid; p < P; p += 512) {
        float4 v = pred[b * P + p]; v.z += 1.0f; v.w += 1.0f;
        int c = cell_of((v.x + v.z) * 0.5f, (v.y + v.w) * 0.5f);
        int r = atomicAdd(&cnt[c], 1);
        pmpc[b * P + p] = c; pmpr[b * P + p] = r;
    }
    __syncthreads();
    if (tid == 0) {
        int s = 0;
        for (int c = 0; c < NCELL; ++c) { cstart[c] = s; s += cnt[c]; }
    }
    __syncthreads();
    for (int p = tid; p < P; p += 512) {
        float4 v = pred[b * P + p]; v.z += 1.0f; v.w += 1.0f;
        sortedP[b * P + cstart[pmpc[b * P + p]] + pmpr[b * P + p]] = v;
    }
}

__global__ __launch_bounds__(256) void giou_main_kernel(
    const float4* __restrict__ sortedT, const float* __restrict__ sTA,
    const float4* __restrict__ sortedP,
    const int* __restrict__ tstartG, const float4* __restrict__ meta0G,
    const float4* __restrict__ meta1G,
    float* __restrict__ partial, int P, int G)
{
    __shared__ float4 sT4[GMAXL];
    __shared__ float  sA[GMAXL];
    __shared__ int    sStart[NCELL + 1];
    __shared__ float4 sM0[NCELL], sM1[NCELL];
    __shared__ float  sOut[4];

    const int b = blockIdx.y, tid = threadIdx.x, lane = tid & 63, wid = tid >> 6;
    const int GL = min(G, GMAXL);
    for (int i = tid; i < GL; i += 256) { sT4[i] = sortedT[b * G + i]; sA[i] = sTA[b * G + i]; }
    if (tid <= NCELL) sStart[tid] = min(tstartG[b * (NCELL + 1) + tid], GMAXL);
    if (tid < NCELL) { sM0[tid] = meta0G[b * NCELL + tid]; sM1[tid] = meta1G[b * NCELL + tid]; }
    __syncthreads();

    const int slot = blockIdx.x * 256 + tid;
    const float4 pb = sortedP[b * P + min(slot, P - 1)];
    const float pw = pb.z - pb.x, ph = pb.w - pb.y, pa = pw * ph;
    const float pxc = (pb.x + pb.z) * 0.5f, pyc = (pb.y + pb.w) * 0.5f;
    const int ownc = cell_of(pxc, pyc);

    float numM = 0.0f, denM = 1.0f;     // running max of giou+1 as num/den

    auto evalT = [&](float4 t, float ta) {
        float iwr = fminf(pb.z, t.z) - fmaxf(pb.x, t.x);
        float ihr = fminf(pb.w, t.w) - fmaxf(pb.y, t.y);
        float inter = fmaxf(iwr, 0.0f) * fmaxf(ihr, 0.0f);
        float un = (pa + ta) - inter;                       // >= 1
        float outer = ((pw + (t.z - t.x)) - iwr) * ((ph + (t.w - t.y)) - ihr);
        float num = __builtin_fmaf(un, un, inter * outer);
        float den = un * outer;                             // >= 1
        bool better = num * denM > numM * den;
        numM = better ? num : numM;
        denM = better ? den : denM;
    };

    // seed: the pred's own cell (per-lane bounds; gather reads)
    for (int i = sStart[ownc]; i < sStart[ownc + 1]; ++i) evalT(sT4[i], sA[i]);

    // cell scan with exact upper-bound pruning
    for (int c = 0; c < NCELL; ++c) {
        const int s = sStart[c], e = sStart[c + 1];
        if (e == s) continue;                               // uniform skip
        const float4 m0 = sM0[c];
        const float4 m1 = sM1[c];
        float dx = fmaxf(0.0f, fmaxf(m0.x - pxc, pxc - m0.z));
        float dy = fmaxf(0.0f, fmaxf(m0.y - pyc, pyc - m0.w));
        bool far_x = dx >= __builtin_fmaf(pw, 0.5f, m1.y);
        bool far_y = dy >= __builtin_fmaf(ph, 0.5f, m1.z);
        bool act;
        if (far_x || far_y) {   // no overlap possible: gi+1 = (pa+ta)/outer
            float ub = (pa + m1.x) *
                       __builtin_amdgcn_rcpf(fmaxf(pw, dx) * fmaxf(ph, dy)) * 1.0002f;
            act = (ub * denM > numM);
        } else {
            act = true;                                      // near cell: must eval
        }
        act = act && (c != ownc);
        if (__any(act)) {
            for (int i = s; i < e; ++i) {                    // uniform bounds,
                if (act) evalT(sT4[i], sA[i]);               // broadcast reads
            }
        }
    }

    // tail if G exceeded LDS capacity (not hit in bench shapes)
    for (int g = GMAXL; g < G; ++g) evalT(sortedT[b * G + g], sTA[b * G + g]);

    float m = numM * __builtin_amdgcn_rcpf(denM);
    float v = (slot < P) ? (2.0f - m) : 0.0f;   // loss = 1 - giou = 2 - (giou+1)
    #pragma unroll
    for (int off = 32; off > 0; off >>= 1) v += __shfl_down(v, off, 64);
    if (lane == 0) sOut[wid] = v;
    __syncthreads();
    if (tid == 0)
        partial[blockIdx.y * gridDim.x + blockIdx.x] = sOut[0] + sOut[1] + sOut[2] + sOut[3];
}

__global__ __launch_bounds__(256) void giou_reduce_kernel(
    const float* __restrict__ partial, float* __restrict__ out, int n, float invB)
{
    const int tid = threadIdx.x;
    float v = 0.0f;
    for (int i = tid; i < n; i += 256) v += partial[i];
    #pragma unroll
    for (int off = 32; off > 0; off >>= 1) v += __shfl_down(v, off, 64);
    __shared__ float sW[4];
    const int wid = tid >> 6;
    if ((tid & 63) == 0) sW[wid] = v;
    __syncthreads();
    if (tid == 0) out[0] = (sW[0] + sW[1] + sW[2] + sW[3]) * invB;
}

extern "C" void kernel_launch(void* const* d_in, const int* in_sizes, int n_in,
                              void* d_out, int out_size, void* d_ws, size_t ws_size,
                              hipStream_t stream) {
    const float* imgs_box = (const float*)d_in[0];  // (B, G, 4) fp32 targets
    const float* pre_box  = (const float*)d_in[1];  // (B, P, 4) fp32 preds
    const int B = in_sizes[2];
    const int G = in_sizes[0] / (4 * B);
    const int P = in_sizes[1] / (4 * B);

    // workspace layout (16B-aligned slabs)
    char* w = (char*)d_ws;
    auto alloc = [&](size_t bytes) {
        char* r = w;
        w += (bytes + 15) & ~size_t(15);
        return r;
    };
    float4* sortedT = (float4*)alloc((size_t)B * G * 16);
    float*  sTA     = (float*) alloc((size_t)B * G * 4);
    float4* sortedP = (float4*)alloc((size_t)B * P * 16);
    int*    tstartG = (int*)   alloc((size_t)B * (NCELL + 1) * 4);
    float4* meta0G  = (float4*)alloc((size_t)B * NCELL * 16);
    float4* meta1G  = (float4*)alloc((size_t)B * NCELL * 16);
    int*    tmpc    = (int*)   alloc((size_t)B * G * 4);
    int*    tmpr    = (int*)   alloc((size_t)B * G * 4);
    int*    pmpc    = (int*)   alloc((size_t)B * P * 4);
    int*    pmpr    = (int*)   alloc((size_t)B * P * 4);
    const int pblocks = (P + 255) / 256;
    float*  partial = (float*) alloc((size_t)pblocks * B * 4);

    giou_prep_kernel<<<B, 512, 0, stream>>>(
        (const float4*)imgs_box, (const float4*)pre_box,
        sortedT, sTA, sortedP, tstartG, meta0G, meta1G,
        tmpc, tmpr, pmpc, pmpr, P, G);

    dim3 grid(pblocks, B);
    giou_main_kernel<<<grid, 256, 0, stream>>>(
        sortedT, sTA, sortedP, tstartG, meta0G, meta1G, partial, P, G);

    giou_reduce_kernel<<<1, 256, 0, stream>>>(
        partial, (float*)d_out, pblocks * B, 1.0f / (float)B);
}

// Round 9
// 46.365 us; speedup vs baseline: 1.7760x; 1.7760x over previous
//
#include <hip/hip_runtime.h>

// GIoU max-match loss: out = (1/B) * sum_{b,p} (1 - max_g GIoU(pred[b,p], tgt[b,g]))
// B=32, P=2048, G=512 in the bench shapes.
//
// R9: cell-grid pruning with R4's occupancy discipline (R8 post-mortem:
// pruning halved VALU work but 1 wave/SIMD + divergent gathers wasted it).
//   prep: counting-sort targets AND preds into an 8x8 grid of 128px cells
//     (cell of box center); per-cell meta: center-bbox, taMax (with margin),
//     max half extents.
//   main (512 thr = 8 waves, NP=2 preds/lane, grid (P/128, B) = 512 blocks
//     -> 4 waves/SIMD):
//     ph1: seed from the block's own cell, waves stride it (uniform reads).
//     exch: cross-wave max via LDS.
//     checks: wave w bound-checks cells [8w,8w+8) for its lanes' pred-pairs
//       (hull form); block-union via __any -> flags. Conservative bound:
//       disjoint-possible test + (paMax+taMax)/(owlb*ohlb), keep unless
//       ub <= mMin - 1e-3.
//     ph2: wave-0 prefix-scans active cell counts -> flat index space;
//       8 waves stride it evenly; all reads wave-uniform broadcast.
//     Wave 0 folds the final max + loss sum -> partial.
//   reduce: tiny second kernel.
// Math (w,h >= 1 after +1 fold): outer via a+b-min identity, no clamps;
//   gi = giou+1 = inter/un + un/outer in (0,2]; clip/eps no-ops at thr=42.24.
//   Pruning is upper-bound-safe: for any target t in cell c,
//     un <= paMax+taMax, outer >= max(pwMin, dxmin+phwMin)*max(phMin, dymin+phhMin),
//     iou <= (x-or-y-disjoint-for-all-t ? 0 : 1).

constexpr int NCX = 8, NCY = 8, NCELL = 64;
constexpr int GCAP = 1024;     // LDS capacity for sorted targets (bench: 512)
constexpr int NP   = 2;        // preds per lane
constexpr int NW   = 8;        // waves per block

__device__ __forceinline__ int cell_of(float xc, float yc) {
    int cx = min(NCX - 1, max(0, (int)(xc * (1.0f / 128.0f))));
    int cy = min(NCY - 1, max(0, (int)(yc * (1.0f / 128.0f))));
    return cy * NCX + cx;
}

__global__ __launch_bounds__(512) void giou_prep_kernel(
    const float4* __restrict__ tgt, const float4* __restrict__ pred,
    float4* __restrict__ sortedT, float* __restrict__ sTA,
    float4* __restrict__ sortedP,
    int* __restrict__ tstartG, float4* __restrict__ meta0G, float4* __restrict__ meta1G,
    int* __restrict__ tc, int* __restrict__ tr,
    int* __restrict__ pc, int* __restrict__ pr,
    int P, int G)
{
    __shared__ int cnt[NCELL], cstart[NCELL + 1];
    __shared__ int mx0[NCELL], my0[NCELL], mx1[NCELL], my1[NCELL];
    __shared__ int mta[NCELL], mhw[NCELL], mhh[NCELL];

    const int b = blockIdx.x, tid = threadIdx.x;
    if (tid < NCELL) {
        cnt[tid] = 0;
        mx0[tid] = 0x7f800000; my0[tid] = 0x7f800000;   // +inf
        mx1[tid] = 0; my1[tid] = 0;
        mta[tid] = 0; mhw[tid] = 0; mhh[tid] = 0;       // values are >= 0
    }
    __syncthreads();

    // targets: count + meta (float atomics via int; all values >= 0)
    for (int g = tid; g < G; g += 512) {
        float4 t = tgt[(size_t)b * G + g]; t.z += 1.0f; t.w += 1.0f;
        float xc = (t.x + t.z) * 0.5f, yc = (t.y + t.w) * 0.5f;
        int c = cell_of(xc, yc);
        tc[(size_t)b * G + g] = c;
        tr[(size_t)b * G + g] = atomicAdd(&cnt[c], 1);
        atomicMin(&mx0[c], __float_as_int(xc));
        atomicMin(&my0[c], __float_as_int(yc));
        atomicMax(&mx1[c], __float_as_int(xc));
        atomicMax(&my1[c], __float_as_int(yc));
        float tw = t.z - t.x, th = t.w - t.y;
        atomicMax(&mta[c], __float_as_int(tw * th));
        atomicMax(&mhw[c], __float_as_int(tw * 0.5f));
        atomicMax(&mhh[c], __float_as_int(th * 0.5f));
    }
    __syncthreads();
    if (tid == 0) {
        int s = 0;
        for (int c = 0; c < NCELL; ++c) { cstart[c] = s; s += cnt[c]; }
        cstart[NCELL] = s;
    }
    __syncthreads();
    for (int g = tid; g < G; g += 512) {
        float4 t = tgt[(size_t)b * G + g]; t.z += 1.0f; t.w += 1.0f;
        int pos = cstart[tc[(size_t)b * G + g]] + tr[(size_t)b * G + g];
        sortedT[(size_t)b * G + pos] = t;
        sTA[(size_t)b * G + pos] = (t.z - t.x) * (t.w - t.y);
    }
    if (tid <= NCELL) tstartG[b * (NCELL + 1) + tid] = cstart[tid];
    if (tid < NCELL) {
        meta0G[b * NCELL + tid] = make_float4(
            __int_as_float(mx0[tid]), __int_as_float(my0[tid]),
            __int_as_float(mx1[tid]), __int_as_float(my1[tid]));
        meta1G[b * NCELL + tid] = make_float4(
            __int_as_float(mta[tid]) * 1.002f + 1.0f,    // margin baked in
            __int_as_float(mhw[tid]), __int_as_float(mhh[tid]), 0.0f);
    }

    // preds: counting sort by cell
    __syncthreads();
    if (tid < NCELL) cnt[tid] = 0;
    __syncthreads();
    for (int p = tid; p < P; p += 512) {
        float4 v = pred[(size_t)b * P + p]; v.z += 1.0f; v.w += 1.0f;
        int c = cell_of((v.x + v.z) * 0.5f, (v.y + v.w) * 0.5f);
        pc[(size_t)b * P + p] = c;
        pr[(size_t)b * P + p] = atomicAdd(&cnt[c], 1);
    }
    __syncthreads();
    if (tid == 0) {
        int s = 0;
        for (int c = 0; c < NCELL; ++c) { cstart[c] = s; s += cnt[c]; }
    }
    __syncthreads();
    for (int p = tid; p < P; p += 512) {
        float4 v = pred[(size_t)b * P + p]; v.z += 1.0f; v.w += 1.0f;
        sortedP[(size_t)b * P + cstart[pc[(size_t)b * P + p]] + pr[(size_t)b * P + p]] = v;
    }
}

__global__ __launch_bounds__(512, 4) void giou_main_kernel(
    const float4* __restrict__ sortedT, const float* __restrict__ sTA,
    const float4* __restrict__ sortedP,
    const int* __restrict__ tstartG, const float4* __restrict__ meta0G,
    const float4* __restrict__ meta1G,
    float* __restrict__ partial, int P, int G)
{
    __shared__ float4 sT[GCAP];
    __shared__ float  sA[GCAP];
    __shared__ int    sStart[NCELL + 1];
    __shared__ float4 sM0[NCELL], sM1[NCELL];
    __shared__ int    sFlag[NCELL];
    __shared__ int    sRcum[NCELL + 1];
    __shared__ float  sEx[NP][512];

    const int b = blockIdx.y, tid = threadIdx.x, lane = tid & 63, wid = tid >> 6;
    const int GL = min(G, GCAP);

    for (int i = tid; i < GL; i += 512) {
        sT[i] = sortedT[(size_t)b * G + i];
        sA[i] = sTA[(size_t)b * G + i];
    }
    if (tid <= NCELL) sStart[tid] = min(tstartG[b * (NCELL + 1) + tid], GL);
    if (tid < NCELL) { sM0[tid] = meta0G[b * NCELL + tid]; sM1[tid] = meta1G[b * NCELL + tid]; }
    __syncthreads();                                         // (1)

    const int base = blockIdx.x * (NP * 64);
    float4 pb[NP]; float pw[NP], ph[NP], pa[NP];
    #pragma unroll
    for (int k = 0; k < NP; ++k) {
        float4 v = sortedP[(size_t)b * P + min(base + 64 * k + lane, P - 1)];
        pb[k] = v; pw[k] = v.z - v.x; ph[k] = v.w - v.y; pa[k] = pw[k] * ph[k];
    }
    // hull precomputes (conservative for both preds)
    float pxc0 = (pb[0].x + pb[0].z) * 0.5f, pyc0 = (pb[0].y + pb[0].w) * 0.5f;
    float pxc1 = (pb[1].x + pb[1].z) * 0.5f, pyc1 = (pb[1].y + pb[1].w) * 0.5f;
    float hx0 = fminf(pxc0, pxc1), hx1 = fmaxf(pxc0, pxc1);
    float hy0 = fminf(pyc0, pyc1), hy1 = fmaxf(pyc0, pyc1);
    float phw0 = pw[0] * 0.5f, phh0 = ph[0] * 0.5f;
    float phw1 = pw[1] * 0.5f, phh1 = ph[1] * 0.5f;
    float phwMin = fminf(phw0, phw1), phhMin = fminf(phh0, phh1);
    float phwMax = fmaxf(phw0, phw1), phhMax = fmaxf(phh0, phh1);
    float pwMin = fminf(pw[0], pw[1]), phMin = fminf(ph[0], ph[1]);
    float paMax = fmaxf(pa[0], pa[1]);

    float m[NP] = {0.0f, 0.0f};     // running max of giou+1 in (0,2]

    auto evalTA = [&](float4 t, float ta) {
        float tw = t.z - t.x, th = t.w - t.y;
        #pragma unroll
        for (int k = 0; k < NP; ++k) {
            float iwr = fminf(pb[k].z, t.z) - fmaxf(pb[k].x, t.x);
            float ihr = fminf(pb[k].w, t.w) - fmaxf(pb[k].y, t.y);
            float inter = fmaxf(iwr, 0.0f) * fmaxf(ihr, 0.0f);
            float un = (pa[k] + ta) - inter;                       // >= 1
            float outer = ((pw[k] + tw) - iwr) * ((ph[k] + th) - ihr);
            float gi = __builtin_fmaf(un, __builtin_amdgcn_rcpf(outer),
                                      inter * __builtin_amdgcn_rcpf(un));
            m[k] = fmaxf(m[k], gi);
        }
    };

    // phase 1: seed from the block's own cell (uniform choice via mid pred)
    float4 midp = sortedP[(size_t)b * P + min(base + 64, P - 1)];
    const int oc = cell_of((midp.x + midp.z) * 0.5f, (midp.y + midp.w) * 0.5f);
    {
        const int s = sStart[oc], e = sStart[oc + 1];
        for (int i = s + wid; i < e; i += NW) evalTA(sT[i], sA[i]);
    }
    sEx[0][tid] = m[0]; sEx[1][tid] = m[1];
    __syncthreads();                                         // (2)
    #pragma unroll
    for (int k = 0; k < NP; ++k) {
        float mm = sEx[k][lane];
        #pragma unroll
        for (int w = 1; w < NW; ++w) mm = fmaxf(mm, sEx[k][w * 64 + lane]);
        m[k] = mm;
    }
    const float mMin = fminf(m[0], m[1]);

    // checks: wave w covers cells [8w, 8w+8); block-union via __any
    for (int cc = 0; cc < 8; ++cc) {
        const int c = wid * 8 + cc;
        const float4 cb = sM0[c];
        const float4 mt = sM1[c];
        float dxm = fmaxf(fmaxf(cb.x - hx1, hx0 - cb.z), 0.0f);
        float dym = fmaxf(fmaxf(cb.y - hy1, hy0 - cb.w), 0.0f);
        bool disj = (dxm >= phwMax + mt.y) || (dym >= phhMax + mt.z);
        float owlb = fmaxf(pwMin, dxm + phwMin);
        float ohlb = fmaxf(phMin, dym + phhMin);
        float areaT = (paMax + mt.x) * __builtin_amdgcn_rcpf(owlb * ohlb);
        float ub = areaT + (disj ? 0.0f : 1.0f);
        bool act = (ub > mMin - 1e-3f) && (c != oc);
        int anyact = __any((int)act);
        if (lane == 0) sFlag[c] = anyact;
    }
    __syncthreads();                                         // (3)
    if (wid == 0) {   // prefix scan of active cell counts (lane = cell)
        int v = sFlag[lane] ? (sStart[lane + 1] - sStart[lane]) : 0;
        #pragma unroll
        for (int off = 1; off < 64; off <<= 1) {
            int n = __shfl_up(v, off, 64);
            if (lane >= off) v += n;
        }
        sRcum[lane + 1] = v;
        if (lane == 0) sRcum[0] = 0;
    }
    __syncthreads();                                         // (4)

    // phase 2: 8 waves stride the flat active-target index space
    {
        const int T = sRcum[NCELL];
        int r = 0, rc1 = sRcum[1], rbase = sStart[0];
        for (int j = wid; j < T; j += NW) {
            while (j >= rc1) { ++r; rc1 = sRcum[r + 1]; rbase = sStart[r] - sRcum[r]; }
            int idx = rbase + j;
            evalTA(sT[idx], sA[idx]);
        }
    }
    // overflow tail (G > GCAP only; bench never hits this)
    for (int g = GCAP + wid; g < G; g += NW)
        evalTA(sortedT[(size_t)b * G + g], sTA[(size_t)b * G + g]);

    sEx[0][tid] = m[0]; sEx[1][tid] = m[1];
    __syncthreads();                                         // (5)
    if (wid == 0) {
        float v = 0.0f;
        #pragma unroll
        for (int k = 0; k < NP; ++k) {
            float mm = sEx[k][lane];
            #pragma unroll
            for (int w = 1; w < NW; ++w) mm = fmaxf(mm, sEx[k][w * 64 + lane]);
            v += (base + 64 * k + lane < P) ? (2.0f - mm) : 0.0f;   // 1-giou
        }
        #pragma unroll
        for (int off = 32; off > 0; off >>= 1) v += __shfl_down(v, off, 64);
        if (lane == 0) partial[blockIdx.y * gridDim.x + blockIdx.x] = v;
    }
}

__global__ __launch_bounds__(256) void giou_reduce_kernel(
    const float* __restrict__ partial, float* __restrict__ out, int n, float invB)
{
    const int tid = threadIdx.x;
    float v = 0.0f;
    for (int i = tid; i < n; i += 256) v += partial[i];
    #pragma unroll
    for (int off = 32; off > 0; off >>= 1) v += __shfl_down(v, off, 64);
    __shared__ float sW[4];
    const int wid = tid >> 6;
    if ((tid & 63) == 0) sW[wid] = v;
    __syncthreads();
    if (tid == 0) out[0] = (sW[0] + sW[1] + sW[2] + sW[3]) * invB;
}

extern "C" void kernel_launch(void* const* d_in, const int* in_sizes, int n_in,
                              void* d_out, int out_size, void* d_ws, size_t ws_size,
                              hipStream_t stream) {
    const float* imgs_box = (const float*)d_in[0];  // (B, G, 4) fp32 targets
    const float* pre_box  = (const float*)d_in[1];  // (B, P, 4) fp32 preds
    const int B = in_sizes[2];
    const int G = in_sizes[0] / (4 * B);
    const int P = in_sizes[1] / (4 * B);

    char* w = (char*)d_ws;
    auto alloc = [&](size_t bytes) {
        char* r = w; w += (bytes + 15) & ~size_t(15); return r;
    };
    float4* sortedT = (float4*)alloc((size_t)B * G * 16);
    float*  sTA     = (float*) alloc((size_t)B * G * 4);
    float4* sortedP = (float4*)alloc((size_t)B * P * 16);
    int*    tstartG = (int*)   alloc((size_t)B * (NCELL + 1) * 4);
    float4* meta0G  = (float4*)alloc((size_t)B * NCELL * 16);
    float4* meta1G  = (float4*)alloc((size_t)B * NCELL * 16);
    int*    tc      = (int*)   alloc((size_t)B * G * 4);
    int*    tr      = (int*)   alloc((size_t)B * G * 4);
    int*    pc      = (int*)   alloc((size_t)B * P * 4);
    int*    pr      = (int*)   alloc((size_t)B * P * 4);
    const int pblocks = (P + NP * 64 - 1) / (NP * 64);       // 128 preds/block
    float*  partial = (float*) alloc((size_t)pblocks * B * 4);

    giou_prep_kernel<<<B, 512, 0, stream>>>(
        (const float4*)imgs_box, (const float4*)pre_box,
        sortedT, sTA, sortedP, tstartG, meta0G, meta1G, tc, tr, pc, pr, P, G);

    dim3 grid(pblocks, B);
    giou_main_kernel<<<grid, 512, 0, stream>>>(
        sortedT, sTA, sortedP, tstartG, meta0G, meta1G, partial, P, G);

    giou_reduce_kernel<<<1, 256, 0, stream>>>(
        partial, (float*)d_out, pblocks * B, 1.0f / (float)B);
}